// Round 9
// baseline (278.626 us; speedup 1.0000x reference)
//
#include <hip/hip_runtime.h>
#include <hip/hip_bf16.h>
#include <stdint.h>

#define LL 2048
#define SS 2048
#define HH 8
#define EE 64
#define RSG 512   // global row stride in elements (H*E)

typedef float v4f  __attribute__((ext_vector_type(4)));
typedef float v16f __attribute__((ext_vector_type(16)));
typedef short s4v  __attribute__((ext_vector_type(4)));
typedef short s8v  __attribute__((ext_vector_type(8)));

// fp32 -> bf16 bits, round-to-nearest-even
__device__ __forceinline__ short f2bf(float f) {
    unsigned u = __float_as_uint(f);
    u = (u + 0x7fffu + ((u >> 16) & 1u)) >> 16;
    return (short)u;
}

__device__ __forceinline__ s4v pack4bf(float a, float b, float c, float d) {
    float2 ab = make_float2(a, b), cd = make_float2(c, d);
    __hip_bfloat162 r0 = __float22bfloat162_rn(ab);
    __hip_bfloat162 r1 = __float22bfloat162_rn(cd);
    s4v r;
    __builtin_memcpy(&r, &r0, 4);
    __builtin_memcpy(((char*)&r) + 4, &r1, 4);
    return r;
}

// ---------------- prepass ----------------
// K and V become per-(b,h,64-row-tile) IMAGES in k-chunk-major order so every
// main-loop ds_read_b128 and global_load_lds is fully linear (0 bank conflicts).
// K image: chunk u = echunk*64 + srow  holds K[srow][8*echunk .. +8) as bf16.
// V image: chunk u = c*64 + e          holds V[perm(c,j)][e], j=0..7, with
//   perm(c,j) = 16*(c>>1) + 4*(c&1) + 8*(j>>2) + (j&3)   (the PV k-permutation)
// Also zeroes the 512 pair-combine counters (graph-replay safe).
__global__ __launch_bounds__(256)
void dsattn_prep(const float* __restrict__ kk, const float* __restrict__ vv,
                 short* __restrict__ kimg, short* __restrict__ vimg,
                 unsigned* __restrict__ ctrb)
{
    __shared__ float T[64][68];
    const int t = threadIdx.x;
    const int blk = blockIdx.x;
    if (blk < 4) { ctrb[blk * 256 + t] = 0u; }   // 1024 uints = 512 pairs x {claim,ready}
    if (blk < 1024) {
        const int vb = blk;                  // (b*8 + h)*32 + ts
        const int b = vb >> 8, h = (vb >> 5) & 7, ts = vb & 31;
        const float* kp = kk + ((size_t)b * SS + ts * 64) * RSG + h * EE;
        #pragma unroll
        for (int c = 0; c < 4; ++c) {
            int idx = c * 256 + t, s = idx >> 4, e0 = (idx & 15) << 2;
            *(v4f*)&T[s][e0] = *(const v4f*)(kp + (size_t)s * RSG + e0);
        }
        __syncthreads();
        short* dst = kimg + (size_t)vb * 4096;
        #pragma unroll
        for (int half = 0; half < 2; ++half) {
            int ci = half * 256 + t;         // chunk u = echunk*64 + srow
            int echunk = ci >> 6, srow = ci & 63;
            s8v ov;
            #pragma unroll
            for (int j = 0; j < 8; ++j) ov[j] = f2bf(T[srow][echunk * 8 + j]);
            *(s8v*)(dst + ci * 8) = ov;
        }
    } else {
        const int vb = blk - 1024;           // (b*8 + h)*32 + ts
        const int b = vb >> 8, h = (vb >> 5) & 7, ts = vb & 31;
        const float* vp = vv + ((size_t)b * SS + ts * 64) * RSG + h * EE;
        #pragma unroll
        for (int c = 0; c < 4; ++c) {
            int idx = c * 256 + t, s = idx >> 4, e0 = (idx & 15) << 2;
            *(v4f*)&T[s][e0] = *(const v4f*)(vp + (size_t)s * RSG + e0);
        }
        __syncthreads();
        short* dst = vimg + (size_t)vb * 4096;
        #pragma unroll
        for (int half = 0; half < 2; ++half) {
            int ci = half * 256 + t;         // chunk u = c*64 + e
            int c = ci >> 6, e = ci & 63;
            int sbase = 16 * (c >> 1) + 4 * (c & 1);
            s8v ov;
            #pragma unroll
            for (int j = 0; j < 8; ++j) {
                int s = sbase + 8 * (j >> 2) + (j & 3);
                ov[j] = f2bf(T[s][e]);
            }
            *(s8v*)(dst + ci * 8) = ov;
        }
    }
}

// ---------------- main: 128 Q x S-HALF per block, 4 waves, 32KB LDS ----------
// DESYNC lever: 1024 independent 256-thread blocks (4 blocks/CU, 16 waves/CU in
// FOUR barrier domains).  Each pair (sh=0/1) covers one (mt,h,b); partials are
// combined cross-block: first finisher publishes unnormalized O^T into `out` +
// rsum into ws, signals via device-scope atomic; survivor adds+normalizes.
// Protocol is dispatch-order independent (the awaited block never blocks).
// Inner loop is the verified r5/r7 structure: 2-slot ring, counted vmcnt(4),
// zero-conflict k-chunk-major images.  XCD-bijective swizzle, sh fastest bit.
__global__ __launch_bounds__(256, 4)
void dsattn_main(const float* __restrict__ q, const short* __restrict__ kimg,
                 const short* __restrict__ vimg, const float* __restrict__ tau,
                 float* __restrict__ out, float* __restrict__ rsumb,
                 unsigned* __restrict__ ctrb)
{
    __shared__ short KV[2][8192];   // per slot: [0..4095] K image, [4096..8191] V image
    __shared__ int role;

    const int t    = threadIdx.x;
    const int lane = t & 63;
    const int w    = t >> 6;
    const int l31  = lane & 31;
    const int hi   = lane >> 5;

    // XCD-aware decode: 1024 blocks, 128 consecutive work-units per XCD.
    // wu bits: sh(1) | mt(4) | h(3) | b(2)  -- sh fastest => pair on same XCD.
    const int hw = blockIdx.x;
    const int wu = (hw & 7) * 128 + (hw >> 3);
    const int sh = wu & 1;
    const int mt = (wu >> 1) & 15;
    const int h  = (wu >> 5) & 7;
    const int b  = wu >> 8;

    const float scf = 0.125f * 1.44269504088896f * tau[b];  // tau*scale*log2e folded into Q

    // ---- Q B-frags: lane holds Q[w*32+l31][e = 16ks + 8hi + j], pre-scaled ----
    s8v qf[4];
    {
        const float* qb = q + ((size_t)b * LL + (size_t)mt * 128 + w * 32 + l31) * RSG
                            + h * EE + 8 * hi;
        #pragma unroll
        for (int ks = 0; ks < 4; ++ks) {
            v4f a0 = *(const v4f*)(qb + 16 * ks);
            v4f a1 = *(const v4f*)(qb + 16 * ks + 4);
            s4v p0 = pack4bf(a0[0] * scf, a0[1] * scf, a0[2] * scf, a0[3] * scf);
            s4v p1 = pack4bf(a1[0] * scf, a1[1] * scf, a1[2] * scf, a1[3] * scf);
            s8v f;
            #pragma unroll
            for (int j = 0; j < 4; ++j) { f[j] = p0[j]; f[4 + j] = p1[j]; }
            qf[ks] = f;
        }
    }

    // ---- staging source: fully linear (K image: waves 0,1; V image: waves 2,3);
    //      this block's S-half starts at tile sh*16 ----
    const char* gsrc;
    {
        const size_t base = ((size_t)((b * 8 + h) * 32 + sh * 16)) * 8192;  // bytes
        if (w < 2) gsrc = (const char*)kimg + base + w * 4096 + lane * 16;
        else       gsrc = (const char*)vimg + base + (w - 2) * 4096 + lane * 16;
    }

    // one STAGE = 4 loads/thread; waves 0,1 fill K (8KB), waves 2,3 fill V (8KB)
    #define STAGE(slot)                                                                   \
        {                                                                                 \
            _Pragma("unroll")                                                             \
            for (int j = 0; j < 4; ++j) {                                                 \
                __builtin_amdgcn_global_load_lds(                                         \
                    (const __attribute__((address_space(1))) unsigned*)(gsrc + j * 1024), \
                    (__attribute__((address_space(3))) unsigned*)&KV[slot][w * 2048 + j * 512], \
                    16, 0, 0);                                                            \
            }                                                                             \
            gsrc += 8192;                                                                 \
        }

    v16f oacc[2];
    #pragma unroll
    for (int mb = 0; mb < 2; ++mb)
        #pragma unroll
        for (int r = 0; r < 16; ++r) oacc[mb][r] = 0.0f;
    float rsum = 0.0f;

    // per-lane fragment offset (shorts): chunk u = (2ks+hi)*64 + mb*32 + l31
    //   -> offset = ks*1024 + mb*256 + rb,  rb = hi*512 + l31*8
    const int rb = hi * 512 + l31 * 8;

    // Drain Q loads so loop vmcnt counts see ONLY staging loads; fill both slots.
    asm volatile("s_waitcnt vmcnt(0)" ::: "memory");
    __builtin_amdgcn_sched_barrier(0);
    STAGE(0);
    STAGE(1);

    #pragma unroll 1
    for (int sw = 0; sw < 16; ++sw) {
        const int p = sw & 1;

        // Outstanding: tiles sw, sw+1 = 8 loads -> vmcnt(4) retires tile sw.
        // Tail sw=15: only 4 outstanding -> vmcnt(0).
        __builtin_amdgcn_sched_barrier(0);
        if (sw <= 14) asm volatile("s_waitcnt vmcnt(4)" ::: "memory");
        else          asm volatile("s_waitcnt vmcnt(0)" ::: "memory");
        __builtin_amdgcn_s_barrier();
        __builtin_amdgcn_sched_barrier(0);

        const short* Kp = &KV[p][0];
        const short* Vp = &KV[p][4096];

        // ---- S^T = K Q^T : 2 s-row-blocks x 4 k-steps ----
        v16f st[2];
        #pragma unroll
        for (int mb = 0; mb < 2; ++mb) {
            v16f z;
            #pragma unroll
            for (int r = 0; r < 16; ++r) z[r] = 0.0f;
            #pragma unroll
            for (int ks = 0; ks < 4; ++ks) {
                s8v kf = *(const s8v*)&Kp[ks * 1024 + mb * 256 + rb];
                z = __builtin_amdgcn_mfma_f32_32x32x16_bf16(kf, qf[ks], z, 0, 0, 0);
            }
            st[mb] = z;
        }

        // ---- exp2 numerator (tau pre-folded, no max-tracking), row sum, pack ----
        #pragma unroll
        for (int mb = 0; mb < 2; ++mb)
            #pragma unroll
            for (int r = 0; r < 16; ++r)
                st[mb][r] = __builtin_amdgcn_exp2f(st[mb][r]);
        float s0 = 0.f, s1 = 0.f;
        #pragma unroll
        for (int r = 0; r < 16; ++r) { s0 += st[0][r]; s1 += st[1][r]; }
        rsum += s0 + s1;

        s8v pf[4];    // B-operand for PV, straight from C-layout registers
        #pragma unroll
        for (int tt = 0; tt < 4; ++tt) {
            int o = 8 * (tt & 1);
            const v16f& sv = st[tt >> 1];
            s4v lo = pack4bf(sv[o + 0], sv[o + 1], sv[o + 2], sv[o + 3]);
            s4v hs = pack4bf(sv[o + 4], sv[o + 5], sv[o + 6], sv[o + 7]);
            s8v f;
            #pragma unroll
            for (int j = 0; j < 4; ++j) { f[j] = lo[j]; f[4 + j] = hs[j]; }
            pf[tt] = f;
        }

        // ---- O^T += V^T P^T : 2 e-row-blocks x 4 k-steps ----
        #pragma unroll
        for (int mb = 0; mb < 2; ++mb) {
            v16f acc = oacc[mb];
            #pragma unroll
            for (int ks = 0; ks < 4; ++ks) {
                s8v vf = *(const s8v*)&Vp[ks * 1024 + mb * 256 + rb];
                acc = __builtin_amdgcn_mfma_f32_32x32x16_bf16(vf, pf[ks], acc, 0, 0, 0);
            }
            oacc[mb] = acc;
        }

        // re-stage the just-computed slot with tile sw+2
        if (sw <= 13) {
            __builtin_amdgcn_sched_barrier(0);
            __builtin_amdgcn_s_barrier();
            __builtin_amdgcn_sched_barrier(0);
            STAGE(p);
        }
    }

    // ---- cross-block pair combine (sh=0/1 of same mt,h,b) ----
    const int pair = wu >> 1;
    unsigned* ctr = ctrb + pair * 2;          // {claim, ready}
    float* rws = rsumb + (size_t)pair * 256;
    float* ob = out + ((size_t)b * LL + (size_t)mt * 128 + w * 32 + l31) * RSG + h * EE;

    __syncthreads();
    if (t == 0) role = (int)atomicAdd(&ctr[0], 1u);
    __syncthreads();

    if (role == 0) {
        // first finisher: publish unnormalized partial O^T + per-thread rsum
        #pragma unroll
        for (int mb = 0; mb < 2; ++mb)
            #pragma unroll
            for (int rq = 0; rq < 4; ++rq) {
                int e0 = 32 * mb + 8 * rq + 4 * hi;
                v4f o4 = { oacc[mb][4 * rq + 0], oacc[mb][4 * rq + 1],
                           oacc[mb][4 * rq + 2], oacc[mb][4 * rq + 3] };
                *(v4f*)(ob + e0) = o4;
            }
        rws[t] = rsum;
        __syncthreads();                      // drains all stores (waitcnt before barrier)
        __threadfence();                      // device-scope release
        if (t == 0) atomicAdd(&ctr[1], 1u);   // ready
    } else {
        // survivor: wait for partner's data (bounded: partner never blocks)
        if (t == 0) {
            while (atomicAdd(&ctr[1], 0u) == 0u) __builtin_amdgcn_s_sleep(2);
        }
        __syncthreads();
        __threadfence();                      // device-scope acquire (invalidate L1)
        rsum += rws[t];
        #pragma unroll
        for (int mb = 0; mb < 2; ++mb)
            #pragma unroll
            for (int rq = 0; rq < 4; ++rq) {
                int e0 = 32 * mb + 8 * rq + 4 * hi;
                v4f pp = *(const v4f*)(ob + e0);
                oacc[mb][4 * rq + 0] += pp[0];
                oacc[mb][4 * rq + 1] += pp[1];
                oacc[mb][4 * rq + 2] += pp[2];
                oacc[mb][4 * rq + 3] += pp[3];
            }
        rsum += __shfl_xor(rsum, 32);         // cross-half: other 32 s-rows per tile
        const float inv = 1.0f / rsum;
        #pragma unroll
        for (int mb = 0; mb < 2; ++mb)
            #pragma unroll
            for (int rq = 0; rq < 4; ++rq) {
                int e0 = 32 * mb + 8 * rq + 4 * hi;   // C row = (reg&3)+8*(reg>>2)+4*hi
                v4f o4 = { oacc[mb][4 * rq + 0] * inv, oacc[mb][4 * rq + 1] * inv,
                           oacc[mb][4 * rq + 2] * inv, oacc[mb][4 * rq + 3] * inv };
                *(v4f*)(ob + e0) = o4;
            }
    }
}

extern "C" void kernel_launch(void* const* d_in, const int* in_sizes, int n_in,
                              void* d_out, int out_size, void* d_ws, size_t ws_size,
                              hipStream_t stream) {
    const float* q     = (const float*)d_in[0];
    const float* k     = (const float*)d_in[1];
    const float* v     = (const float*)d_in[2];
    // d_in[3] = attn_mask (unused); d_in[5] = delta (drops out of softmax exactly)
    const float* tau   = (const float*)d_in[4];
    float* out = (float*)d_out;

    short*    kimg  = (short*)d_ws;                       // 8.39 MB
    short*    vimg  = kimg + (size_t)4 * SS * RSG;        // 8.39 MB
    float*    rsumb = (float*)(vimg + (size_t)4 * SS * RSG);  // 512 pairs x 256 = 0.52 MB
    unsigned* ctrb  = (unsigned*)(rsumb + (size_t)512 * 256); // 512 pairs x 2 = 4 KB

    dsattn_prep<<<dim3(2048), dim3(256), 0, stream>>>(k, v, kimg, vimg, ctrb);
    dsattn_main<<<dim3(1024), dim3(256), 0, stream>>>(q, kimg, vimg, tau, out, rsumb, ctrb);
}

// Round 10
// 139.996 us; speedup vs baseline: 1.9902x; 1.9902x over previous
//
#include <hip/hip_runtime.h>
#include <hip/hip_bf16.h>
#include <stdint.h>

#define LL 2048
#define SS 2048
#define HH 8
#define EE 64
#define RSG 512   // global row stride in elements (H*E)

typedef float v4f  __attribute__((ext_vector_type(4)));
typedef float v16f __attribute__((ext_vector_type(16)));
typedef short s4v  __attribute__((ext_vector_type(4)));
typedef short s8v  __attribute__((ext_vector_type(8)));

// fp32 -> bf16 bits, round-to-nearest-even
__device__ __forceinline__ short f2bf(float f) {
    unsigned u = __float_as_uint(f);
    u = (u + 0x7fffu + ((u >> 16) & 1u)) >> 16;
    return (short)u;
}

__device__ __forceinline__ s4v pack4bf(float a, float b, float c, float d) {
    float2 ab = make_float2(a, b), cd = make_float2(c, d);
    __hip_bfloat162 r0 = __float22bfloat162_rn(ab);
    __hip_bfloat162 r1 = __float22bfloat162_rn(cd);
    s4v r;
    __builtin_memcpy(&r, &r0, 4);
    __builtin_memcpy(((char*)&r) + 4, &r1, 4);
    return r;
}

// ---------------- prepass (verified r5 version) ----------------
// K and V become per-(b,h,64-row-tile) IMAGES in k-chunk-major order so every
// main-loop ds_read_b128 and global_load_lds is fully linear (0 bank conflicts).
// K image: chunk u = echunk*64 + srow  holds K[srow][8*echunk .. +8) as bf16.
// V image: chunk u = c*64 + e          holds V[perm(c,j)][e], j=0..7, with
//   perm(c,j) = 16*(c>>1) + 4*(c&1) + 8*(j>>2) + (j&3)   (the PV k-permutation)
__global__ __launch_bounds__(256)
void dsattn_prep(const float* __restrict__ kk, const float* __restrict__ vv,
                 short* __restrict__ kimg, short* __restrict__ vimg)
{
    __shared__ float T[64][68];
    const int t = threadIdx.x;
    const int blk = blockIdx.x;
    if (blk < 1024) {
        const int vb = blk;                  // (b*8 + h)*32 + ts
        const int b = vb >> 8, h = (vb >> 5) & 7, ts = vb & 31;
        const float* kp = kk + ((size_t)b * SS + ts * 64) * RSG + h * EE;
        #pragma unroll
        for (int c = 0; c < 4; ++c) {
            int idx = c * 256 + t, s = idx >> 4, e0 = (idx & 15) << 2;
            *(v4f*)&T[s][e0] = *(const v4f*)(kp + (size_t)s * RSG + e0);
        }
        __syncthreads();
        short* dst = kimg + (size_t)vb * 4096;
        #pragma unroll
        for (int half = 0; half < 2; ++half) {
            int ci = half * 256 + t;         // chunk u = echunk*64 + srow
            int echunk = ci >> 6, srow = ci & 63;
            s8v ov;
            #pragma unroll
            for (int j = 0; j < 8; ++j) ov[j] = f2bf(T[srow][echunk * 8 + j]);
            *(s8v*)(dst + ci * 8) = ov;
        }
    } else {
        const int vb = blk - 1024;           // (b*8 + h)*32 + ts
        const int b = vb >> 8, h = (vb >> 5) & 7, ts = vb & 31;
        const float* vp = vv + ((size_t)b * SS + ts * 64) * RSG + h * EE;
        #pragma unroll
        for (int c = 0; c < 4; ++c) {
            int idx = c * 256 + t, s = idx >> 4, e0 = (idx & 15) << 2;
            *(v4f*)&T[s][e0] = *(const v4f*)(vp + (size_t)s * RSG + e0);
        }
        __syncthreads();
        short* dst = vimg + (size_t)vb * 4096;
        #pragma unroll
        for (int half = 0; half < 2; ++half) {
            int ci = half * 256 + t;         // chunk u = c*64 + e
            int c = ci >> 6, e = ci & 63;
            int sbase = 16 * (c >> 1) + 4 * (c & 1);
            s8v ov;
            #pragma unroll
            for (int j = 0; j < 8; ++j) {
                int s = sbase + 8 * (j >> 2) + (j & 3);
                ov[j] = f2bf(T[s][e]);
            }
            *(s8v*)(dst + ci * 8) = ov;
        }
    }
}

// ---------------- main: 64 Q rows/block, 2 waves, full S sweep, 32KB LDS -----
// DESYNC lever (no cross-block dataflow this time): 1024 independent 128-thread
// blocks -> 5 blocks/CU = 5 separate barrier domains (10 waves/CU).  Blocks
// drift out of phase, so one block's MFMA phase overlaps another's exp/LDS
// phase — breaking the lockstep phase-sum that r0-r7 measured (~sum of pipes).
// Inner loop per block = verified r5 structure: 2-slot ring, counted vmcnt(8)
// (8 loads/stage: wave 0 stages K, wave 1 stages V), zero-conflict images.
// No combine: each block owns its 64 Q rows end-to-end (exact softmax).
// XCD-bijective swizzle, mt fastest -> consecutive blocks share a (b,h) panel.
__global__ __launch_bounds__(128, 2)
void dsattn_main(const float* __restrict__ q, const short* __restrict__ kimg,
                 const short* __restrict__ vimg, const float* __restrict__ tau,
                 float* __restrict__ out)
{
    __shared__ short KV[2][8192];   // per slot: [0..4095] K image, [4096..8191] V image

    const int t    = threadIdx.x;
    const int lane = t & 63;
    const int w    = t >> 6;        // 0,1
    const int l31  = lane & 31;
    const int hi   = lane >> 5;

    // XCD-aware decode: 1024 blocks, 128 consecutive work-units per XCD.
    // wu bits: mt(5) | h(3) | b(2), mt fastest.
    const int hw = blockIdx.x;
    const int wu = (hw & 7) * 128 + (hw >> 3);
    const int mt = wu & 31;
    const int h  = (wu >> 5) & 7;
    const int b  = wu >> 8;

    const float scf = 0.125f * 1.44269504088896f * tau[b];  // tau*scale*log2e folded into Q

    // ---- Q B-frags: lane holds Q[mt*64 + w*32 + l31][e = 16ks + 8hi + j], pre-scaled ----
    s8v qf[4];
    {
        const float* qb = q + ((size_t)b * LL + (size_t)mt * 64 + w * 32 + l31) * RSG
                            + h * EE + 8 * hi;
        #pragma unroll
        for (int ks = 0; ks < 4; ++ks) {
            v4f a0 = *(const v4f*)(qb + 16 * ks);
            v4f a1 = *(const v4f*)(qb + 16 * ks + 4);
            s4v p0 = pack4bf(a0[0] * scf, a0[1] * scf, a0[2] * scf, a0[3] * scf);
            s4v p1 = pack4bf(a1[0] * scf, a1[1] * scf, a1[2] * scf, a1[3] * scf);
            s8v f;
            #pragma unroll
            for (int j = 0; j < 4; ++j) { f[j] = p0[j]; f[4 + j] = p1[j]; }
            qf[ks] = f;
        }
    }

    // ---- staging source: fully linear; wave 0 -> K image, wave 1 -> V image ----
    const char* gsrc;
    {
        const size_t pan = (size_t)((b * 8 + h) * 32) * 8192;   // 32 tiles x 8KB
        gsrc = (const char*)(w ? vimg : kimg) + pan + lane * 16;
    }

    // one STAGE = 8 loads/thread: wave 0 fills K half (8KB), wave 1 fills V half
    #define STAGE(slot)                                                                   \
        {                                                                                 \
            _Pragma("unroll")                                                             \
            for (int j = 0; j < 8; ++j) {                                                 \
                __builtin_amdgcn_global_load_lds(                                         \
                    (const __attribute__((address_space(1))) unsigned*)(gsrc + j * 1024), \
                    (__attribute__((address_space(3))) unsigned*)&KV[slot][w * 4096 + j * 512], \
                    16, 0, 0);                                                            \
            }                                                                             \
            gsrc += 8192;                                                                 \
        }

    v16f oacc[2];
    #pragma unroll
    for (int mb = 0; mb < 2; ++mb)
        #pragma unroll
        for (int r = 0; r < 16; ++r) oacc[mb][r] = 0.0f;
    float rsum = 0.0f;

    // per-lane fragment offset (shorts): chunk u = (2ks+hi)*64 + mb*32 + l31
    //   -> offset = ks*1024 + mb*256 + rb,  rb = hi*512 + l31*8
    const int rb = hi * 512 + l31 * 8;

    // Drain Q loads so loop vmcnt counts see ONLY staging loads; fill both slots.
    asm volatile("s_waitcnt vmcnt(0)" ::: "memory");
    __builtin_amdgcn_sched_barrier(0);
    STAGE(0);
    STAGE(1);

    #pragma unroll 1
    for (int sw = 0; sw < 32; ++sw) {
        const int p = sw & 1;

        // Outstanding: tiles sw, sw+1 = 16 loads -> vmcnt(8) retires tile sw.
        // Tail sw=31: only 8 outstanding -> vmcnt(0).
        __builtin_amdgcn_sched_barrier(0);
        if (sw <= 30) asm volatile("s_waitcnt vmcnt(8)" ::: "memory");
        else          asm volatile("s_waitcnt vmcnt(0)" ::: "memory");
        __builtin_amdgcn_s_barrier();
        __builtin_amdgcn_sched_barrier(0);

        const short* Kp = &KV[p][0];
        const short* Vp = &KV[p][4096];

        // ---- S^T = K Q^T : 2 s-row-blocks x 4 k-steps ----
        v16f st[2];
        #pragma unroll
        for (int mb = 0; mb < 2; ++mb) {
            v16f z;
            #pragma unroll
            for (int r = 0; r < 16; ++r) z[r] = 0.0f;
            #pragma unroll
            for (int ks = 0; ks < 4; ++ks) {
                s8v kf = *(const s8v*)&Kp[ks * 1024 + mb * 256 + rb];
                z = __builtin_amdgcn_mfma_f32_32x32x16_bf16(kf, qf[ks], z, 0, 0, 0);
            }
            st[mb] = z;
        }

        // ---- exp2 numerator (tau pre-folded, no max-tracking), row sum, pack ----
        #pragma unroll
        for (int mb = 0; mb < 2; ++mb)
            #pragma unroll
            for (int r = 0; r < 16; ++r)
                st[mb][r] = __builtin_amdgcn_exp2f(st[mb][r]);
        float s0 = 0.f, s1 = 0.f;
        #pragma unroll
        for (int r = 0; r < 16; ++r) { s0 += st[0][r]; s1 += st[1][r]; }
        rsum += s0 + s1;

        s8v pf[4];    // B-operand for PV, straight from C-layout registers
        #pragma unroll
        for (int tt = 0; tt < 4; ++tt) {
            int o = 8 * (tt & 1);
            const v16f& sv = st[tt >> 1];
            s4v lo = pack4bf(sv[o + 0], sv[o + 1], sv[o + 2], sv[o + 3]);
            s4v hs = pack4bf(sv[o + 4], sv[o + 5], sv[o + 6], sv[o + 7]);
            s8v f;
            #pragma unroll
            for (int j = 0; j < 4; ++j) { f[j] = lo[j]; f[4 + j] = hs[j]; }
            pf[tt] = f;
        }

        // ---- O^T += V^T P^T : 2 e-row-blocks x 4 k-steps ----
        #pragma unroll
        for (int mb = 0; mb < 2; ++mb) {
            v16f acc = oacc[mb];
            #pragma unroll
            for (int ks = 0; ks < 4; ++ks) {
                s8v vf = *(const s8v*)&Vp[ks * 1024 + mb * 256 + rb];
                acc = __builtin_amdgcn_mfma_f32_32x32x16_bf16(vf, pf[ks], acc, 0, 0, 0);
            }
            oacc[mb] = acc;
        }

        // re-stage the just-computed slot with tile sw+2
        if (sw <= 29) {
            __builtin_amdgcn_sched_barrier(0);
            __builtin_amdgcn_s_barrier();
            __builtin_amdgcn_sched_barrier(0);
            STAGE(p);
        }
    }

    // ---- denominator (single cross-half reduce) and store O^T -> O ----
    rsum += __shfl_xor(rsum, 32);
    const float inv = 1.0f / rsum;
    float* ob = out + ((size_t)b * LL + (size_t)mt * 64 + w * 32 + l31) * RSG + h * EE;
    #pragma unroll
    for (int mb = 0; mb < 2; ++mb)
        #pragma unroll
        for (int rq = 0; rq < 4; ++rq) {
            int e0 = 32 * mb + 8 * rq + 4 * hi;     // C-layout row = (reg&3)+8*(reg>>2)+4*hi
            v4f o4 = { oacc[mb][4 * rq + 0] * inv, oacc[mb][4 * rq + 1] * inv,
                       oacc[mb][4 * rq + 2] * inv, oacc[mb][4 * rq + 3] * inv };
            *(v4f*)(ob + e0) = o4;
        }
}

extern "C" void kernel_launch(void* const* d_in, const int* in_sizes, int n_in,
                              void* d_out, int out_size, void* d_ws, size_t ws_size,
                              hipStream_t stream) {
    const float* q     = (const float*)d_in[0];
    const float* k     = (const float*)d_in[1];
    const float* v     = (const float*)d_in[2];
    // d_in[3] = attn_mask (unused); d_in[5] = delta (drops out of softmax exactly)
    const float* tau   = (const float*)d_in[4];
    float* out = (float*)d_out;

    short* kimg = (short*)d_ws;                   // 4*2048*512 bf16 = 8.39 MB
    short* vimg = kimg + (size_t)4 * SS * RSG;    // 8.39 MB

    dsattn_prep<<<dim3(2048), dim3(256), 0, stream>>>(k, v, kimg, vimg);
    dsattn_main<<<dim3(1024), dim3(128), 0, stream>>>(q, kimg, vimg, tau, out);
}

// Round 11
// 135.619 us; speedup vs baseline: 2.0545x; 1.0323x over previous
//
#include <hip/hip_runtime.h>
#include <hip/hip_bf16.h>
#include <stdint.h>

#define LL 2048
#define SS 2048
#define HH 8
#define EE 64
#define RSG 512   // global row stride in elements (H*E)

typedef float v4f  __attribute__((ext_vector_type(4)));
typedef float v16f __attribute__((ext_vector_type(16)));
typedef short s4v  __attribute__((ext_vector_type(4)));
typedef short s8v  __attribute__((ext_vector_type(8)));

// fp32 -> bf16 bits, round-to-nearest-even
__device__ __forceinline__ short f2bf(float f) {
    unsigned u = __float_as_uint(f);
    u = (u + 0x7fffu + ((u >> 16) & 1u)) >> 16;
    return (short)u;
}

__device__ __forceinline__ s4v pack4bf(float a, float b, float c, float d) {
    float2 ab = make_float2(a, b), cd = make_float2(c, d);
    __hip_bfloat162 r0 = __float22bfloat162_rn(ab);
    __hip_bfloat162 r1 = __float22bfloat162_rn(cd);
    s4v r;
    __builtin_memcpy(&r, &r0, 4);
    __builtin_memcpy(((char*)&r) + 4, &r1, 4);
    return r;
}

// ---------------- prepass (BANDWIDTH-OPTIMIZED rewrite) ----------------
// Same images as the verified r5 prep (bit-identical: RNE at load = RNE at
// emit), but each block owns one (tensor, b, 64-row tile) for ALL 8 heads:
//   - global reads are fully contiguous 2KB rows (perfect coalescing;
//     the old prep read 256B runs strided 2KB per (b,h) slice)
//   - fp32->bf16 at load; LDS stages bf16 (32 x 520, 1040B rows = 16B aligned)
//   - per-head emits are 16B/thread contiguous writes (coalesced runs)
// K image: chunk u = echunk*64 + srow  holds K[srow][8*echunk .. +8) as bf16.
// V image: chunk u = c*64 + e          holds V[perm(c,j)][e], j=0..7, with
//   perm(c,j) = 16*(c>>1) + 4*(c&1) + 8*(j>>2) + (j&3)   (the PV k-permutation)
__global__ __launch_bounds__(256)
void dsattn_prep(const float* __restrict__ kk, const float* __restrict__ vv,
                 short* __restrict__ kimg, short* __restrict__ vimg)
{
    __shared__ short T[32][520];         // 32 rows x 512 bf16 (+8 pad)
    const int t   = threadIdx.x;
    const int blk = blockIdx.x;          // 0..255
    const int isV = blk >> 7;            // 0: K-tensor, 1: V-tensor
    const int b   = (blk & 127) >> 5;
    const int ts  = blk & 31;
    const float* src = (isV ? vv : kk) + ((size_t)b * SS + ts * 64) * RSG;
    short* dimg = isV ? vimg : kimg;

    #pragma unroll 1
    for (int half = 0; half < 2; ++half) {
        // ---- load 32 rows x 512 fp32 (contiguous rows), convert, stage bf16 ----
        const float* hsrc = src + (size_t)(half * 32) * RSG;
        #pragma unroll
        for (int i = 0; i < 16; ++i) {
            int g = i * 256 + t;                   // v4f slot: row = g>>7, col = (g&127)*4
            int row = g >> 7, c4 = (g & 127) << 2;
            v4f d = *(const v4f*)(hsrc + (size_t)row * RSG + c4);
            *(s4v*)&T[row][c4] = pack4bf(d[0], d[1], d[2], d[3]);
        }
        __syncthreads();

        if (!isV) {
            // K emit: thread t -> chunk u = echunk*64 + half*32 + srow (16B copy)
            const int echunk = t >> 5, srow = t & 31;
            const s8v kv = *(const s8v*)&T[srow][0 * 64 + echunk * 8];  // h folded below
            (void)kv;
            #pragma unroll
            for (int h = 0; h < 8; ++h) {
                s8v ov = *(const s8v*)&T[srow][h * 64 + echunk * 8];
                short* dst = dimg + ((size_t)((b * 8 + h) * 32 + ts)) * 4096
                           + (echunk * 64 + half * 32 + srow) * 8;
                *(s8v*)dst = ov;
            }
        } else {
            // V emit: thread t -> chunk u = c*64 + e, c = (t>>6) + half*4
            const int c = (t >> 6) + half * 4, e = t & 63;
            const int sbase = 16 * (c >> 1) + 4 * (c & 1) - half * 32;  // local row 0..31
            #pragma unroll
            for (int h = 0; h < 8; ++h) {
                s8v ov;
                #pragma unroll
                for (int j = 0; j < 8; ++j) {
                    int s = sbase + 8 * (j >> 2) + (j & 3);
                    ov[j] = T[s][h * 64 + e];
                }
                short* dst = dimg + ((size_t)((b * 8 + h) * 32 + ts)) * 4096
                           + (c * 64 + e) * 8;
                *(s8v*)dst = ov;
            }
        }
        __syncthreads();                 // T reused next half
    }
}

// ---------------- main: VERBATIM round-5 kernel (best verified: 47.2us) -----
// 128 Q rows/block, 4 waves x 32 rows, all-32x32x16 MFMA.  4-slot LDS ring,
// depth-3 prefetch, counted vmcnt(8) (never 0 in steady state), same-tile
// QK->exp->PV.  k-chunk-major K/V images -> every ds_read_b128 is two
// contiguous 512B runs (zero bank conflicts), every global_load_lds linear.
// XCD-bijective 1-D grid: each XCD owns 4 contiguous (b,h) panels.
__global__ __launch_bounds__(256, 2)
void dsattn_main(const float* __restrict__ q, const short* __restrict__ kimg,
                 const short* __restrict__ vimg, const float* __restrict__ tau,
                 float* __restrict__ out)
{
    __shared__ short KV[4][8192];   // per slot: [0..4095] K image, [4096..8191] V image

    const int t    = threadIdx.x;
    const int lane = t & 63;
    const int w    = t >> 6;
    const int l31  = lane & 31;
    const int hi   = lane >> 5;

    // XCD-aware decode: 512 blocks, 8 XCDs, 64 consecutive work-units per XCD.
    const int hw = blockIdx.x;
    const int wu = (hw & 7) * 64 + (hw >> 3);
    const int mt = wu & 15;
    const int h  = (wu >> 4) & 7;
    const int b  = wu >> 7;

    const float scf = 0.125f * 1.44269504088896f * tau[b];  // tau*scale*log2e folded into Q

    // ---- Q B-frags: lane holds Q[w*32+l31][e = 16ks + 8hi + j], pre-scaled ----
    s8v qf[4];
    {
        const float* qb = q + ((size_t)b * LL + (size_t)mt * 128 + w * 32 + l31) * RSG
                            + h * EE + 8 * hi;
        #pragma unroll
        for (int ks = 0; ks < 4; ++ks) {
            v4f a0 = *(const v4f*)(qb + 16 * ks);
            v4f a1 = *(const v4f*)(qb + 16 * ks + 4);
            s4v p0 = pack4bf(a0[0] * scf, a0[1] * scf, a0[2] * scf, a0[3] * scf);
            s4v p1 = pack4bf(a1[0] * scf, a1[1] * scf, a1[2] * scf, a1[3] * scf);
            s8v f;
            #pragma unroll
            for (int j = 0; j < 4; ++j) { f[j] = p0[j]; f[4 + j] = p1[j]; }
            qf[ks] = f;
        }
    }

    // ---- staging source: fully linear (K image: waves 0,1; V image: waves 2,3) ----
    const char* gsrc;
    {
        const size_t pan = (size_t)((b * 8 + h) * 32) * 8192;   // 32 tiles x 8KB
        if (w < 2) gsrc = (const char*)kimg + pan + w * 4096 + lane * 16;
        else       gsrc = (const char*)vimg + pan + (w - 2) * 4096 + lane * 16;
    }

    #define STAGE(slot)                                                                   \
        {                                                                                 \
            _Pragma("unroll")                                                             \
            for (int j = 0; j < 4; ++j) {                                                 \
                __builtin_amdgcn_global_load_lds(                                         \
                    (const __attribute__((address_space(1))) unsigned*)(gsrc + j * 1024), \
                    (__attribute__((address_space(3))) unsigned*)&KV[slot][w * 2048 + j * 512], \
                    16, 0, 0);                                                            \
            }                                                                             \
            gsrc += 8192;                                                                 \
        }

    v16f oacc[2];
    #pragma unroll
    for (int mb = 0; mb < 2; ++mb)
        #pragma unroll
        for (int r = 0; r < 16; ++r) oacc[mb][r] = 0.0f;
    float rsum = 0.0f;

    // per-lane fragment offset (shorts): chunk u = (2ks+hi)*64 + mb*32 + l31
    //   -> offset = ks*1024 + mb*256 + rb,  rb = hi*512 + l31*8
    const int rb = hi * 512 + l31 * 8;

    // Drain Q loads so loop vmcnt counts see ONLY staging loads, then fill pipe 3 deep.
    asm volatile("s_waitcnt vmcnt(0)" ::: "memory");
    __builtin_amdgcn_sched_barrier(0);
    STAGE(0);
    STAGE(1);
    STAGE(2);

    #pragma unroll 4
    for (int it = 0; it < 32; ++it) {
        const int p = it & 3;

        // Outstanding before wait: tiles it, it+1, it+2 = 12 loads -> vmcnt(8)
        // retires tile it.  Tail: it=30 -> 8 outstanding -> vmcnt(4); it=31 -> 0.
        __builtin_amdgcn_sched_barrier(0);
        if (it <= 29)      asm volatile("s_waitcnt vmcnt(8)" ::: "memory");
        else if (it == 30) asm volatile("s_waitcnt vmcnt(4)" ::: "memory");
        else               asm volatile("s_waitcnt vmcnt(0)" ::: "memory");
        __builtin_amdgcn_s_barrier();
        __builtin_amdgcn_sched_barrier(0);

        // prefetch tile it+3 into slot (it+3)&3 = (it-1)&3 (its readers finished
        // during iter it-1; all waves passed the barrier above since)
        if (it <= 28) STAGE((it + 3) & 3);

        const short* Kp = &KV[p][0];
        const short* Vp = &KV[p][4096];

        // ---- S^T = K Q^T : 2 s-row-blocks x 4 k-steps ----
        v16f st[2];
        #pragma unroll
        for (int mb = 0; mb < 2; ++mb) {
            v16f z;
            #pragma unroll
            for (int r = 0; r < 16; ++r) z[r] = 0.0f;
            #pragma unroll
            for (int ks = 0; ks < 4; ++ks) {
                s8v kf = *(const s8v*)&Kp[ks * 1024 + mb * 256 + rb];
                z = __builtin_amdgcn_mfma_f32_32x32x16_bf16(kf, qf[ks], z, 0, 0, 0);
            }
            st[mb] = z;
        }

        // ---- exp2 numerator (tau pre-folded, no max-tracking), row sum, pack P frags ----
        #pragma unroll
        for (int mb = 0; mb < 2; ++mb)
            #pragma unroll
            for (int r = 0; r < 16; ++r)
                st[mb][r] = __builtin_amdgcn_exp2f(st[mb][r]);
        float s0 = 0.f, s1 = 0.f;
        #pragma unroll
        for (int r = 0; r < 16; ++r) { s0 += st[0][r]; s1 += st[1][r]; }
        rsum += s0 + s1;

        s8v pf[4];    // B-operand for PV, straight from C-layout registers
        #pragma unroll
        for (int tt = 0; tt < 4; ++tt) {
            int o = 8 * (tt & 1);
            const v16f& sv = st[tt >> 1];
            s4v lo = pack4bf(sv[o + 0], sv[o + 1], sv[o + 2], sv[o + 3]);
            s4v hs = pack4bf(sv[o + 4], sv[o + 5], sv[o + 6], sv[o + 7]);
            s8v f;
            #pragma unroll
            for (int j = 0; j < 4; ++j) { f[j] = lo[j]; f[4 + j] = hs[j]; }
            pf[tt] = f;
        }

        // ---- O^T += V^T P^T : 2 e-row-blocks x 4 k-steps ----
        #pragma unroll
        for (int mb = 0; mb < 2; ++mb) {
            v16f acc = oacc[mb];
            #pragma unroll
            for (int ks = 0; ks < 4; ++ks) {
                s8v vf = *(const s8v*)&Vp[ks * 1024 + mb * 256 + rb];
                acc = __builtin_amdgcn_mfma_f32_32x32x16_bf16(vf, pf[ks], acc, 0, 0, 0);
            }
            oacc[mb] = acc;
        }
    }

    // ---- denominator (single cross-half reduce) and store O^T -> O ----
    rsum += __shfl_xor(rsum, 32);
    const float inv = 1.0f / rsum;
    float* ob = out + ((size_t)b * LL + (size_t)mt * 128 + w * 32 + l31) * RSG + h * EE;
    #pragma unroll
    for (int mb = 0; mb < 2; ++mb)
        #pragma unroll
        for (int rq = 0; rq < 4; ++rq) {
            int e0 = 32 * mb + 8 * rq + 4 * hi;     // C-layout row = (reg&3)+8*(reg>>2)+4*hi
            v4f o4 = { oacc[mb][4 * rq + 0] * inv, oacc[mb][4 * rq + 1] * inv,
                       oacc[mb][4 * rq + 2] * inv, oacc[mb][4 * rq + 3] * inv };
            *(v4f*)(ob + e0) = o4;
        }
}

extern "C" void kernel_launch(void* const* d_in, const int* in_sizes, int n_in,
                              void* d_out, int out_size, void* d_ws, size_t ws_size,
                              hipStream_t stream) {
    const float* q     = (const float*)d_in[0];
    const float* k     = (const float*)d_in[1];
    const float* v     = (const float*)d_in[2];
    // d_in[3] = attn_mask (unused); d_in[5] = delta (drops out of softmax exactly)
    const float* tau   = (const float*)d_in[4];
    float* out = (float*)d_out;

    short* kimg = (short*)d_ws;                   // 4*2048*512 bf16 = 8.39 MB
    short* vimg = kimg + (size_t)4 * SS * RSG;    // 8.39 MB

    dsattn_prep<<<dim3(256), dim3(256), 0, stream>>>(k, v, kimg, vimg);
    dsattn_main<<<dim3(512), dim3(256), 0, stream>>>(q, kimg, vimg, tau, out);
}